// Round 1
// baseline (30.755 us; speedup 1.0000x reference)
//
#include <hip/hip_runtime.h>
#include <math.h>

#define N_PTS 4000000
#define NQUADS (N_PTS / 4)          // 1,000,000 groups of 4 points (12 floats = 3 float4)
#define NBLOCKS 2048
#define NTHREADS 256

__device__ __constant__ float kMIN_D = 1.0f;
__device__ __constant__ float kMAX_D = 10.0f;

// ---------------------------------------------------------------------------
// Kernel 0: one thread computes R = Rx@Ry@Rz and T from the pose scalars.
// rt[0..8] = R row-major (R[i][j] = rt[3i+j]), rt[9..11] = T.
// ---------------------------------------------------------------------------
__global__ void pose_prep(const float* __restrict__ x, const float* __restrict__ y,
                          const float* __restrict__ z, const float* __restrict__ roll,
                          const float* __restrict__ pitch, const float* __restrict__ yaw,
                          float* __restrict__ rt) {
    float r = roll[0], p = pitch[0], ya = yaw[0];
    float cr = cosf(r),  sr = sinf(r);
    float cp = cosf(p),  sp = sinf(p);
    float cy = cosf(ya), sy = sinf(ya);
    // R = Rx @ Ry @ Rz
    rt[0] = cp * cy;                 rt[1] = -cp * sy;                rt[2] = sp;
    rt[3] = cr * sy + sr * sp * cy;  rt[4] = cr * cy - sr * sp * sy;  rt[5] = -sr * cp;
    rt[6] = sr * sy - cr * sp * cy;  rt[7] = sr * cy + cr * sp * sy;  rt[8] = cr * cp;
    rt[9] = x[0]; rt[10] = y[0]; rt[11] = z[0];
}

// ---------------------------------------------------------------------------
// Kernel 1: streaming pass. 4 points per thread-iteration via 3x float4.
// Writes masked verts, accumulates obs into partials[blockIdx.x].
// ---------------------------------------------------------------------------
__global__ __launch_bounds__(NTHREADS) void proj_kernel(
    const float4* __restrict__ pts, const float* __restrict__ rt,
    float4* __restrict__ vout, float* __restrict__ partials) {

    const float R00 = rt[0], R01 = rt[1], R02 = rt[2];
    const float R10 = rt[3], R11 = rt[4], R12 = rt[5];
    const float R20 = rt[6], R21 = rt[7], R22 = rt[8];
    const float Tx = rt[9], Ty = rt[10], Tz = rt[11];

    float acc = 0.0f;
    const int tid    = blockIdx.x * blockDim.x + threadIdx.x;
    const int stride = gridDim.x * blockDim.x;

    for (int q = tid; q < NQUADS; q += stride) {
        const float4 a = pts[3 * q + 0];
        const float4 b = pts[3 * q + 1];
        const float4 c = pts[3 * q + 2];

        const float px[4] = {a.x, a.w, b.z, c.y};
        const float py[4] = {a.y, b.x, b.w, c.z};
        const float pz[4] = {a.z, b.y, c.x, c.w};
        float vx[4], vy[4], vz[4];

#pragma unroll
        for (int k = 0; k < 4; ++k) {
            const float q0 = px[k] - Tx;
            const float q1 = py[k] - Ty;
            const float q2 = pz[k] - Tz;
            // v = q @ R   (v_j = sum_i q_i * R[i][j])
            const float v0 = q0 * R00 + q1 * R10 + q2 * R20;
            const float v1 = q0 * R01 + q1 * R11 + q2 * R21;
            const float v2 = q0 * R02 + q1 * R12 + q2 * R22;

            const bool dist = (v2 > kMIN_D) && (v2 < kMAX_D);

            // ph = v @ K^T ; ph2 == v2
            const float ph0 = v0 * 600.0f + v2 * 640.0f;
            const float ph1 = v1 * 600.0f + v2 * 360.0f;
            const float u = ph0 / v2;
            const float w = ph1 / v2;
            const bool fov = (v2 > 0.0f) && (u > 1.0f) && (u < 1279.0f) &&
                             (w > 1.0f) && (w < 719.0f);
            const bool m = dist && fov;

            const float d  = sqrtf(v0 * v0 + v1 * v1 + v2 * v2);
            const float t  = (d - 4.0f) * 0.5f;           // (d - MU) / SIGMA
            if (m) acc += expf(-0.5f * t * t);

            vx[k] = m ? v0 : 0.0f;
            vy[k] = m ? v1 : 0.0f;
            vz[k] = m ? v2 : 0.0f;
        }

        float4 o0 = make_float4(vx[0], vy[0], vz[0], vx[1]);
        float4 o1 = make_float4(vy[1], vz[1], vx[2], vy[2]);
        float4 o2 = make_float4(vz[2], vx[3], vy[3], vz[3]);
        vout[3 * q + 0] = o0;
        vout[3 * q + 1] = o1;
        vout[3 * q + 2] = o2;
    }

    // Block reduction (deterministic: fixed tree order).
    __shared__ float sdata[NTHREADS / 64];
#pragma unroll
    for (int off = 32; off > 0; off >>= 1)
        acc += __shfl_down(acc, off, 64);
    if ((threadIdx.x & 63) == 0) sdata[threadIdx.x >> 6] = acc;
    __syncthreads();
    if (threadIdx.x == 0) {
        float tot = 0.0f;
#pragma unroll
        for (int i = 0; i < NTHREADS / 64; ++i) tot += sdata[i];
        partials[blockIdx.x] = tot;
    }
}

// ---------------------------------------------------------------------------
// Kernel 2: sum the 2048 block partials (fixed order) -> loss.
// ---------------------------------------------------------------------------
__global__ __launch_bounds__(256) void loss_kernel(const float* __restrict__ partials,
                                                   int n, float* __restrict__ loss_out) {
    __shared__ float sdata[4];
    float acc = 0.0f;
    for (int i = threadIdx.x; i < n; i += 256) acc += partials[i];
#pragma unroll
    for (int off = 32; off > 0; off >>= 1)
        acc += __shfl_down(acc, off, 64);
    if ((threadIdx.x & 63) == 0) sdata[threadIdx.x >> 6] = acc;
    __syncthreads();
    if (threadIdx.x == 0) {
        float tot = sdata[0] + sdata[1] + sdata[2] + sdata[3];
        loss_out[0] = 1.0f / (tot + 1e-6f);
    }
}

extern "C" void kernel_launch(void* const* d_in, const int* in_sizes, int n_in,
                              void* d_out, int out_size, void* d_ws, size_t ws_size,
                              hipStream_t stream) {
    const float4* pts  = (const float4*)d_in[0];
    const float* x     = (const float*)d_in[1];
    const float* y     = (const float*)d_in[2];
    const float* z     = (const float*)d_in[3];
    const float* roll  = (const float*)d_in[4];
    const float* pitch = (const float*)d_in[5];
    const float* yaw   = (const float*)d_in[6];

    float* out   = (float*)d_out;                 // [0 .. 12M) verts, [12M] loss
    float* ws    = (float*)d_ws;
    float* parts = ws;                            // NBLOCKS floats
    float* rt    = ws + 4096;                     // 12 floats (R + T)

    pose_prep<<<1, 1, 0, stream>>>(x, y, z, roll, pitch, yaw, rt);
    proj_kernel<<<NBLOCKS, NTHREADS, 0, stream>>>(pts, rt, (float4*)out, parts);
    loss_kernel<<<1, 256, 0, stream>>>(parts, NBLOCKS, out + (size_t)3 * N_PTS);
}